// Round 7
// baseline (210.727 us; speedup 1.0000x reference)
//
#include <hip/hip_runtime.h>

// SimpleDialogGNN on MI355X.
// Pipeline (4 launches):
//   K0 prep_kernel    : fused {transpose_pack + msg_pack}
//   K1 gemm<2048,EPI1>: h = xcat @ wt_cat^T + biases; relu/substitute -> rbuf
//   K2 gemm<1024,EPI2>: z = x + rbuf @ wt_out^T + b_out -> fp32 zbuf
//   K3 ln_kernel      : LayerNorm(z) * gamma + beta -> out
//
// GEMM core (this round): r6 geometry (128x128 tile, 512 thr / 8 waves,
// grid 512 = 2 blocks/CU, 16 waves/CU) but restructured to OVERLAP the LDS
// and MFMA pipes, which r6's counters showed perfectly serialized
// (LDS 73.7k cyc + MFMA 33k cyc ~= 107k ~= 116k measured):
//   - BK=32, 4-slot LDS rotation (64 KiB/block, unchanged total)
//   - register ping-pong: body t issues ds_reads for tile t+1 (slot valid
//     since vmcnt one body earlier) + stage(t+3), then sched_barrier(0),
//     then MFMAs tile t — reads drain on LDS pipe DURING the MFMA cluster.
//   - vmcnt(2) per body (counted, never 0 until tail); barrier per body
//     bounds wave skew to 1 body (WAR-safe for slot reuse).
//   - swizzle for BK=32: physical slot = chunk ^ ((row>>1)&3) -> 2-way
//     bank access (free); stage keeps linear LDS dest + pre-swizzled src.
//
// ws layout: [0,32M) xcat (bf16, aliased by zbuf fp32 after GEMM1)
//            [32M,48M) rbuf  [48M,52M) wt_cat  [52M,54M) wt_out

typedef unsigned short u16;
typedef float floatx4 __attribute__((ext_vector_type(4)));
typedef short shortx8 __attribute__((ext_vector_type(8)));

#define T_ 1024
#define H_ 1024

__device__ __forceinline__ float bf2f(u16 v) {
    return __uint_as_float(((unsigned)v) << 16);
}
__device__ __forceinline__ u16 f2bf(float f) {  // round-to-nearest-even
    unsigned u = __float_as_uint(f);
    return (u16)((u + 0x7fffu + ((u >> 16) & 1u)) >> 16);
}
__device__ __forceinline__ void async16(const void* g, void* l) {
    __builtin_amdgcn_global_load_lds(
        (__attribute__((address_space(1))) void*)g,
        (__attribute__((address_space(3))) void*)l, 16, 0, 0);
}
__device__ __forceinline__ void barrier_mem() {
    asm volatile("" ::: "memory");
    __builtin_amdgcn_s_barrier();
    asm volatile("" ::: "memory");
}

// ---------------- K0: fused weight-pack + message aggregation ----------------
__global__ __launch_bounds__(256)
void prep_kernel(const float* __restrict__ x, const float* __restrict__ qmask,
                 const int* __restrict__ dia_len,
                 const float* __restrict__ Wself, const float* __restrict__ Wmsg,
                 const float* __restrict__ Wout,
                 u16* __restrict__ xcat, u16* __restrict__ wt_cat,
                 u16* __restrict__ wt_out)
{
    __shared__ u16 sx[32][1024];  // 64 KiB (transpose path reuses a corner)
    const int tid = threadIdx.x;
    const int bx = blockIdx.x;

    if (bx >= 512) {
        // ---- transpose + bf16 pack of one 32x32 weight tile ----
        const int id = bx - 512;            // 0..3071
        const int wid = id >> 10;           // 0..2
        const int rest = id & 1023;
        const int n0 = (rest & 31) * 32, k0 = (rest >> 5) * 32;
        const float* src = (wid == 0) ? Wself : ((wid == 1) ? Wmsg : Wout);
        float (*s)[33] = reinterpret_cast<float (*)[33]>(&sx[0][0]);
        const int tx = tid & 31, ty = tid >> 5;  // 32x8
#pragma unroll
        for (int i = 0; i < 4; ++i) {
            int k = k0 + ty + 8 * i;
            s[ty + 8 * i][tx] = src[(size_t)k * H_ + n0 + tx];
        }
        __syncthreads();
#pragma unroll
        for (int i = 0; i < 4; ++i) {
            int n = n0 + ty + 8 * i;
            u16 v = f2bf(s[tx][ty + 8 * i]);
            if (wid < 2) wt_cat[(size_t)n * 2048 + wid * 1024 + k0 + tx] = v;
            else         wt_out[(size_t)n * 1024 + k0 + tx] = v;
        }
        return;
    }

    // ---- msg_pack: stage 32 rows (halo 8 each side) as bf16 in LDS ----
    const int b = bx >> 6;
    const int t0 = (bx & 63) * 16;
    const int dlen = dia_len[b];
    const int c4 = tid * 4;
    const float* xb = x + (size_t)b * T_ * H_;

    unsigned spkmask = 0;
#pragma unroll 4
    for (int r = 0; r < 32; ++r) {
        int row = t0 - 8 + r;
        row = row < 0 ? 0 : (row > T_ - 1 ? T_ - 1 : row);
        const float* q = qmask + ((size_t)b * T_ + row) * 2;
        spkmask |= (q[1] > q[0] ? 1u : 0u) << r;
        float4 v = *(const float4*)(xb + (size_t)row * H_ + c4);
        ushort4 u;
        u.x = f2bf(v.x); u.y = f2bf(v.y); u.z = f2bf(v.z); u.w = f2bf(v.w);
        *(ushort4*)&sx[r][c4] = u;
    }
    __syncthreads();

    for (int lt = 0; lt < 16; ++lt) {
        const int t = t0 + lt;
        const unsigned cs = (spkmask >> (lt + 8)) & 1u;
        float a0 = 0.f, a1 = 0.f, a2 = 0.f, a3 = 0.f;
        int cnt = 0;
#pragma unroll
        for (int o = 0; o < 17; ++o) {
            const int idx = t + o - 8;
            if (idx >= 0 && idx < dlen) {  // block-uniform branch
                const float w = (((spkmask >> (lt + o)) & 1u) == cs) ? 1.0f : 0.5f;
                ++cnt;
                ushort4 u = *(const ushort4*)&sx[lt + o][c4];
                a0 += w * bf2f(u.x); a1 += w * bf2f(u.y);
                a2 += w * bf2f(u.z); a3 += w * bf2f(u.w);
            }
        }
        const float inv = 1.0f / (float)(cnt > 0 ? cnt : 1);
        ushort4 m;
        m.x = f2bf(a0 * inv); m.y = f2bf(a1 * inv);
        m.z = f2bf(a2 * inv); m.w = f2bf(a3 * inv);
        const size_t rowg = (size_t)b * T_ + t;
        *(ushort4*)&xcat[rowg * 2048 + 1024 + c4] = m;
        *(ushort4*)&xcat[rowg * 2048 + c4] = *(const ushort4*)&sx[lt + 8][c4];
    }
}

// ---------------- K1/K2: bf16 MFMA GEMM, pipelined LDS/MFMA overlap ----------
// A: M x K row-major bf16; Bt: N x K row-major bf16 (N-major).
// Swizzle: logical (row, 16B-chunk c) at physical slot c ^ ((row>>1)&3).

#define LOADSET(AV, BV, TT) do {                                              \
    const u16* pA_ = &sA[(TT) & 3][0];                                        \
    const u16* pB_ = &sB[(TT) & 3][0];                                        \
    AV[0] = *(const shortx8*)(pA_ + aOff0);                                   \
    AV[1] = *(const shortx8*)(pA_ + aOff1);                                   \
    BV[0] = *(const shortx8*)(pB_ + bOff0);                                   \
    BV[1] = *(const shortx8*)(pB_ + bOff1);                                   \
    BV[2] = *(const shortx8*)(pB_ + bOff2);                                   \
    BV[3] = *(const shortx8*)(pB_ + bOff3);                                   \
} while (0)

#define GBODY(TT, AC, BC, AN, BNV) do {                                       \
    if ((TT) + 1 < NT) LOADSET(AN, BNV, (TT) + 1);                            \
    if ((TT) + 3 < NT) stage((TT) + 3);                                       \
    __builtin_amdgcn_sched_barrier(0);                                        \
    __builtin_amdgcn_s_setprio(1);                                            \
    acc[0][0] = __builtin_amdgcn_mfma_f32_16x16x32_bf16(AC[0], BC[0], acc[0][0], 0, 0, 0); \
    acc[1][0] = __builtin_amdgcn_mfma_f32_16x16x32_bf16(AC[1], BC[0], acc[1][0], 0, 0, 0); \
    acc[0][1] = __builtin_amdgcn_mfma_f32_16x16x32_bf16(AC[0], BC[1], acc[0][1], 0, 0, 0); \
    acc[1][1] = __builtin_amdgcn_mfma_f32_16x16x32_bf16(AC[1], BC[1], acc[1][1], 0, 0, 0); \
    acc[0][2] = __builtin_amdgcn_mfma_f32_16x16x32_bf16(AC[0], BC[2], acc[0][2], 0, 0, 0); \
    acc[1][2] = __builtin_amdgcn_mfma_f32_16x16x32_bf16(AC[1], BC[2], acc[1][2], 0, 0, 0); \
    acc[0][3] = __builtin_amdgcn_mfma_f32_16x16x32_bf16(AC[0], BC[3], acc[0][3], 0, 0, 0); \
    acc[1][3] = __builtin_amdgcn_mfma_f32_16x16x32_bf16(AC[1], BC[3], acc[1][3], 0, 0, 0); \
    __builtin_amdgcn_s_setprio(0);                                            \
    if ((TT) + 1 < NT) {                                                      \
        if ((TT) + 3 < NT) asm volatile("s_waitcnt vmcnt(2)" ::: "memory");   \
        else               asm volatile("s_waitcnt vmcnt(0)" ::: "memory");   \
        barrier_mem();                                                        \
    }                                                                         \
} while (0)

template <int K, int EPI>
__global__ __launch_bounds__(512, 4)
void gemm_bt(const u16* __restrict__ A, const u16* __restrict__ Bt,
             const float* __restrict__ bias1, const float* __restrict__ bias2,
             const float* __restrict__ X, const int* __restrict__ dia_len,
             u16* __restrict__ Rout, float* __restrict__ Zout)
{
    constexpr int NT = K / 32;
    static_assert(NT >= 4 && (NT & 1) == 0, "NT even, >=4");
    __shared__ u16 sA[4][128 * 32];  // 32 KiB
    __shared__ u16 sB[4][128 * 32];  // 32 KiB
    const int tid = threadIdx.x;

    // T1: XCD-aware block map (verified ~ideal FETCH r3-r6).
    const int bid = blockIdx.x;
    const int xcd = bid & 7, li = bid >> 3;     // li in [0,64)
    const int mt = xcd * 8 + (li >> 3);         // 0..63
    const int nt = li & 7;                      // 0..7
    const int bm = mt * 128, bn = nt * 128;

    const int wave = tid >> 6, lane = tid & 63;
    const int wr = wave >> 1, wc = wave & 1;    // 4M x 2N waves, 32x64 C each
    const int lrow = lane & 15, lq = lane >> 4;

    // ---- staging: 512 thr x 16B = one 128x32 operand tile per async16 ----
    const int srow = tid >> 2;                  // 0..127
    const int sl   = (tid & 3) ^ ((srow >> 1) & 3);  // pre-swizzled chunk
    const u16* Asrc = A + (size_t)(bm + srow) * K + sl * 8;
    const u16* Bsrc = Bt + (size_t)(bn + srow) * K + sl * 8;

    auto stage = [&](int t) {                   // 2 async16 per thread
        const int s = t & 3;
        async16(Asrc + t * 32, &sA[s][tid * 8]);
        async16(Bsrc + t * 32, &sB[s][tid * 8]);
    };

    floatx4 acc[2][4];
#pragma unroll
    for (int i = 0; i < 2; ++i)
#pragma unroll
        for (int j = 0; j < 4; ++j)
            acc[i][j] = (floatx4){0.f, 0.f, 0.f, 0.f};

    // ---- compute-side element offsets (loop-invariant, swizzled) ----
    const int ra0 = wr * 32 + lrow,      ra1 = ra0 + 16;
    const int rb0 = wc * 64 + lrow,      rb1 = rb0 + 16,
              rb2 = rb0 + 32,            rb3 = rb0 + 48;
    const int aOff0 = ra0 * 32 + (lq ^ ((ra0 >> 1) & 3)) * 8;
    const int aOff1 = ra1 * 32 + (lq ^ ((ra1 >> 1) & 3)) * 8;
    const int bOff0 = rb0 * 32 + (lq ^ ((rb0 >> 1) & 3)) * 8;
    const int bOff1 = rb1 * 32 + (lq ^ ((rb1 >> 1) & 3)) * 8;
    const int bOff2 = rb2 * 32 + (lq ^ ((rb2 >> 1) & 3)) * 8;
    const int bOff3 = rb3 * 32 + (lq ^ ((rb3 >> 1) & 3)) * 8;

    // ---- prologue: 3 tiles in flight; t0,t1 landed before first reads ----
    stage(0); stage(1); stage(2);
    asm volatile("s_waitcnt vmcnt(2)" ::: "memory");
    barrier_mem();

    shortx8 aP[2], bP[4], aQ[2], bQ[4];
    LOADSET(aP, bP, 0);

    for (int t = 0; t < NT; t += 2) {
        GBODY(t,     aP, bP, aQ, bQ);
        GBODY(t + 1, aQ, bQ, aP, bP);
    }

    // epilogue — C/D mapping: col = lane&15, row = (lane>>4)*4 + reg
    const int dl = (EPI == 1) ? dia_len[bm >> 10] : 0;  // b uniform per block
#pragma unroll
    for (int i = 0; i < 2; ++i) {
        const int row0 = bm + wr * 32 + i * 16 + lq * 4;
#pragma unroll
        for (int j = 0; j < 4; ++j) {
            const int col = bn + wc * 64 + j * 16 + lrow;
#pragma unroll
            for (int r = 0; r < 4; ++r) {
                const int row = row0 + r;
                const float v = acc[i][j][r];
                if (EPI == 1) {
                    const float h = v + bias1[col] + bias2[col];
                    float outv;
                    if ((row & (T_ - 1)) < dl) {
                        outv = h;  // majority path: no X read
                    } else {
                        outv = X[(size_t)row * H_ + col];
                    }
                    Rout[(size_t)row * H_ + col] = f2bf(fmaxf(outv, 0.f));
                } else {
                    const float z = X[(size_t)row * H_ + col] + v + bias1[col];
                    Zout[(size_t)row * H_ + col] = z;
                }
            }
        }
    }
}

// ---------------- K3: LayerNorm ---------------------------------------------
__global__ __launch_bounds__(256)
void ln_kernel(const float* __restrict__ Z, const float* __restrict__ gamma,
               const float* __restrict__ beta, float* __restrict__ out)
{
    const int row = blockIdx.x;
    const int tid = threadIdx.x;
    const size_t base = (size_t)row * H_ + tid * 4;
    float4 v = *(const float4*)(Z + base);
    float s = v.x + v.y + v.z + v.w;
    float q = v.x * v.x + v.y * v.y + v.z * v.z + v.w * v.w;
#pragma unroll
    for (int off = 32; off > 0; off >>= 1) {
        s += __shfl_down(s, off);
        q += __shfl_down(q, off);
    }
    __shared__ float ps[4], pq[4];
    const int wave = tid >> 6, lane = tid & 63;
    if (lane == 0) { ps[wave] = s; pq[wave] = q; }
    __syncthreads();
    const float S = ps[0] + ps[1] + ps[2] + ps[3];
    const float Q = pq[0] + pq[1] + pq[2] + pq[3];
    const float mean = S * (1.0f / 1024.0f);
    const float var = Q * (1.0f / 1024.0f) - mean * mean;
    const float inv = rsqrtf(var + 1e-5f);
    float4 g = *(const float4*)(gamma + tid * 4);
    float4 bt = *(const float4*)(beta + tid * 4);
    float4 o;
    o.x = g.x * (v.x - mean) * inv + bt.x;
    o.y = g.y * (v.y - mean) * inv + bt.y;
    o.z = g.z * (v.z - mean) * inv + bt.z;
    o.w = g.w * (v.w - mean) * inv + bt.w;
    *(float4*)(out + base) = o;
}

// ---------------- launcher ---------------------------------------------------
extern "C" void kernel_launch(void* const* d_in, const int* in_sizes, int n_in,
                              void* d_out, int out_size, void* d_ws, size_t ws_size,
                              hipStream_t stream)
{
    (void)in_sizes; (void)n_in; (void)out_size; (void)ws_size;
    const float* x       = (const float*)d_in[0];
    const float* qmask   = (const float*)d_in[1];
    const int*   dia_len = (const int*)d_in[2];
    const float* W_msg   = (const float*)d_in[5];
    const float* b_msg   = (const float*)d_in[6];
    const float* W_self  = (const float*)d_in[7];
    const float* b_self  = (const float*)d_in[8];
    const float* W_out   = (const float*)d_in[9];
    const float* b_out   = (const float*)d_in[10];
    const float* gamma   = (const float*)d_in[11];
    const float* beta    = (const float*)d_in[12];
    float* out = (float*)d_out;

    char* ws = (char*)d_ws;
    u16*   xcat   = (u16*)ws;                           // 32 MiB
    u16*   rbuf   = (u16*)(ws + (size_t)(32u << 20));   // 16 MiB
    u16*   wt_cat = (u16*)(ws + (size_t)(48u << 20));   // 4 MiB
    u16*   wt_out = (u16*)(ws + (size_t)(52u << 20));   // 2 MiB
    float* zbuf   = (float*)ws;                         // alias xcat (safe: GEMM2 no longer reads xcat)

    prep_kernel<<<dim3(3584), 256, 0, stream>>>(x, qmask, dia_len,
                                                W_self, W_msg, W_out,
                                                xcat, wt_cat, wt_out);
    gemm_bt<2048, 1><<<dim3(512), 512, 0, stream>>>(xcat, wt_cat, b_self, b_msg,
                                                    x, dia_len, rbuf, nullptr);
    gemm_bt<1024, 2><<<dim3(512), 512, 0, stream>>>(rbuf, wt_out, b_out, nullptr,
                                                    x, nullptr, nullptr, zbuf);
    ln_kernel<<<dim3(8192), 256, 0, stream>>>(zbuf, gamma, beta, out);
}